// Round 2
// baseline (1875.404 us; speedup 1.0000x reference)
//
#include <hip/hip_runtime.h>

#define Hh 32
#define Ww 128
#define BB 32
#define CC 16
#define OO 128
#define DEPTH 4
#define SPIN_CAP (1 << 25)

typedef __attribute__((ext_vector_type(8))) short short8;
typedef __attribute__((ext_vector_type(4))) float f32x4;

__device__ inline short f2bf(float f) {
    unsigned u = __builtin_bit_cast(unsigned, f);
    unsigned r = (u + 0x7FFFu + ((u >> 16) & 1u)) >> 16;
    return (short)r;
}

__device__ inline float sigm(float x) { return 1.f / (1.f + __expf(-x)); }
__device__ inline float tanh_(float x) {
    float xc = fminf(fmaxf(x, -10.f), 10.f);
    float e = __expf(2.f * xc);
    return (e - 1.f) / (e + 1.f);
}

__device__ inline unsigned long long aload64(const unsigned long long* p) {
    return __hip_atomic_load(p, __ATOMIC_RELAXED, __HIP_MEMORY_SCOPE_AGENT);
}
__device__ inline void astore64(unsigned long long* p, unsigned long long v) {
    __hip_atomic_store(p, v, __ATOMIC_RELAXED, __HIP_MEMORY_SCOPE_AGENT);
}
__device__ inline float aloadf(const float* p) {
    return __hip_atomic_load(p, __ATOMIC_RELAXED, __HIP_MEMORY_SCOPE_AGENT);
}
__device__ inline void astoref(float* p, float v) {
    __hip_atomic_store(p, v, __ATOMIC_RELAXED, __HIP_MEMORY_SCOPE_AGENT);
}

// ---- init: zero flags, transpose x (B,C,H,W) fp32 -> xT (H,W,B,C) bf16 ----
__global__ void mdlstm_init(const float* __restrict__ x, short* __restrict__ xT,
                            int* __restrict__ flags) {
    int idx = blockIdx.x * 256 + threadIdx.x;
    if (blockIdx.x == 0) {
        flags[threadIdx.x] = 0;
        flags[256 + threadIdx.x] = 0;
    }
    int w = idx & 127;
    int h = (idx >> 7) & 31;
    int c = (idx >> 12) & 15;
    int b = idx >> 16;
    float v = x[idx];
    xT[((h * Ww + w) * BB + b) * CC + c] = f2bf(v);
}

// ---- main persistent wavefront kernel (plain launch: 256 blocks on 256 CUs,
//      __launch_bounds__(256,1) guarantees >=1 block/CU => fully co-resident) ----
__global__ void __launch_bounds__(256, 1) mdlstm_main(
    const short* __restrict__ xT,
    const float* __restrict__ w_ii, const float* __restrict__ w_hi, const float* __restrict__ b_i,
    const float* __restrict__ w_if, const float* __restrict__ w_hf, const float* __restrict__ b_f,
    const float* __restrict__ w_ig, const float* __restrict__ w_hg, const float* __restrict__ b_g,
    const float* __restrict__ w_io, const float* __restrict__ w_ho, const float* __restrict__ b_o,
    const float* __restrict__ wsum, const float* __restrict__ bias,
    short* __restrict__ hring, float* __restrict__ cring,
    int* __restrict__ prog, int* __restrict__ cons,
    float* __restrict__ out)
{
    const int chain = blockIdx.x & 7;       // d*2+s  -> one XCD per chain (perf heuristic)
    const int r     = blockIdx.x >> 3;      // scan row 0..31
    const int d     = chain >> 1;
    const int s     = chain & 1;
    const int b0    = s * 16;
    const bool fy   = (d >= 2);
    const bool fx   = (d & 1);
    const int hh    = fy ? (Hh - 1 - r) : r;

    const int tid  = threadIdx.x;
    const int wv   = tid >> 6;
    const int lane = tid & 63;
    const int lr   = lane & 15;   // A-operand m / B-operand n / D col
    const int lh   = lane >> 4;   // quad
    const int nb   = wv * 32;     // this wave's output-column base

    __shared__ short lds_h[16 * 136];   // +8 pad per row: 2-way max bank alias on b128 reads

    // ---------- weight fragments (registers, loaded once) ----------
    const float* whp[4] = {w_hi, w_hf, w_hg, w_ho};
    const float* wip[4] = {w_ii, w_if, w_ig, w_io};
    short8 whf[4][2][4];   // [gate][ntile][ktile] B-frag: W[n][k]
    short8 wif_[4][2];     // input-proj B-frag (k<16 valid, rest 0)
#pragma unroll
    for (int g = 0; g < 4; ++g) {
#pragma unroll
        for (int nt = 0; nt < 2; ++nt) {
            const int n = nb + nt * 16 + lr;
#pragma unroll
            for (int kt = 0; kt < 4; ++kt) {
                const float* p = whp[g] + ((d * OO + n) * OO + kt * 32 + lh * 8);
                short8 f;
#pragma unroll
                for (int j = 0; j < 8; ++j) f[j] = f2bf(p[j]);
                whf[g][nt][kt] = f;
            }
            short8 fi = (short8)(short)0;
            if (lh < 2) {
                const float* p = wip[g] + ((d * OO + n) * CC + lh * 8);
#pragma unroll
                for (int j = 0; j < 8; ++j) fi[j] = f2bf(p[j]);
            }
            wif_[g][nt] = fi;
        }
    }

    // per-lane biases (D-layout columns)
    float bi[2], bff[2], bg[2], bo[2], bb[2];
#pragma unroll
    for (int nt = 0; nt < 2; ++nt) {
        int n = d * OO + nb + nt * 16 + lr;
        bi[nt] = b_i[n]; bff[nt] = b_f[n]; bg[nt] = b_g[n]; bo[nt] = b_o[n]; bb[nt] = bias[n];
    }
    const float ws0 = wsum[d * 2 + 0];
    const float ws1 = wsum[d * 2 + 1];

    // flags
    int* topf      = prog + ((d * 32 + (r - 1)) * 2 + s);   // valid if r>0
    int* myprog    = prog + ((d * 32 + r) * 2 + s);
    int* mycons    = cons + ((d * 32 + r) * 2 + s);
    int* consnext  = cons + ((d * 32 + (r + 1)) * 2 + s);   // valid if r<31

    // ring bases (element units; hring shorts, cring floats — same element counts)
    const int rb_me  = (d * 32 + r) * DEPTH * BB * OO;
    const int rb_top = (d * 32 + (r - 1)) * DEPTH * BB * OO;

    // output address bases (D-layout)
    int obase[2][4];
#pragma unroll
    for (int nt = 0; nt < 2; ++nt)
#pragma unroll
        for (int j = 0; j < 4; ++j)
            obase[nt][j] = ((d * OO + nb + nt * 16 + lr) * BB + (b0 + lh * 4 + j)) * (Hh * Ww) + hh * Ww;

    // recurrent state
    short8 hLf[4];
#pragma unroll
    for (int kt = 0; kt < 4; ++kt) hLf[kt] = (short8)(short)0;
    float cL[2][4];
#pragma unroll
    for (int nt = 0; nt < 2; ++nt)
#pragma unroll
        for (int j = 0; j < 4; ++j) cL[nt][j] = 0.f;

    int top_seen = 0, cons_seen = 0;
    const f32x4 zacc = {0.f, 0.f, 0.f, 0.f};

    for (int wsc = 0; wsc < Ww; ++wsc) {
        const int ww   = fx ? (Ww - 1 - wsc) : wsc;
        const int slot = wsc & (DEPTH - 1);

        // x input fragment (A-layout, K=16 zero-padded to 32)
        short8 xf = (short8)(short)0;
        if (lh < 2) {
            const short* p = xT + ((hh * Ww + ww) * BB + b0 + lr) * CC + lh * 8;
            xf = *(const short8*)p;
        }

        // back-pressure: don't overwrite ring slot until consumer is done with it
        if (r < 31 && wsc >= DEPTH) {
            const int need = wsc - DEPTH + 1;
            int spin = 0;
            while (cons_seen < need && spin < SPIN_CAP) {
                int v = 0;
                if (lane == 0) v = __hip_atomic_load(consnext, __ATOMIC_RELAXED, __HIP_MEMORY_SCOPE_AGENT);
                v = __shfl(v, 0, 64);
                if (v < need) { __builtin_amdgcn_s_sleep(2); ++spin; } else cons_seen = v;
            }
        }

        // top dependency
        short8 hTf[4];
        float cT[2][4];
        if (r > 0) {
            const int need = wsc + 1;
            int spin = 0;
            while (top_seen < need && spin < SPIN_CAP) {
                int v = 0;
                if (lane == 0) v = __hip_atomic_load(topf, __ATOMIC_RELAXED, __HIP_MEMORY_SCOPE_AGENT);
                v = __shfl(v, 0, 64);
                if (v < need) { __builtin_amdgcn_s_sleep(2); ++spin; } else top_seen = v;
            }
            const int hb = rb_top + slot * BB * OO + (b0 + lr) * OO;
#pragma unroll
            for (int kt = 0; kt < 4; ++kt) {
                const unsigned long long* p = (const unsigned long long*)(hring + hb + kt * 32 + lh * 8);
                union { unsigned long long q[2]; short8 v; } u;
                u.q[0] = aload64(p);
                u.q[1] = aload64(p + 1);
                hTf[kt] = u.v;
            }
            const int cb = rb_top + slot * BB * OO;
#pragma unroll
            for (int nt = 0; nt < 2; ++nt)
#pragma unroll
                for (int j = 0; j < 4; ++j)
                    cT[nt][j] = aloadf(cring + cb + (b0 + lh * 4 + j) * OO + nb + nt * 16 + lr);
        } else {
#pragma unroll
            for (int kt = 0; kt < 4; ++kt) hTf[kt] = (short8)(short)0;
#pragma unroll
            for (int nt = 0; nt < 2; ++nt)
#pragma unroll
                for (int j = 0; j < 4; ++j) cT[nt][j] = 0.f;
        }

        // ---------- MFMA: preact = x@Wi^T (+ h@Wh^T), both branches ----------
        f32x4 accT[4][2], accL[4][2];
#pragma unroll
        for (int g = 0; g < 4; ++g) {
#pragma unroll
            for (int nt = 0; nt < 2; ++nt) {
                f32x4 ax = __builtin_amdgcn_mfma_f32_16x16x32_bf16(xf, wif_[g][nt], zacc, 0, 0, 0);
                f32x4 at = ax, al = ax;
#pragma unroll
                for (int kt = 0; kt < 4; ++kt) {
                    at = __builtin_amdgcn_mfma_f32_16x16x32_bf16(hTf[kt], whf[g][nt][kt], at, 0, 0, 0);
                    al = __builtin_amdgcn_mfma_f32_16x16x32_bf16(hLf[kt], whf[g][nt][kt], al, 0, 0, 0);
                }
                accT[g][nt] = at;
                accL[g][nt] = al;
            }
        }

        // ---------- elementwise LSTM cell (D-layout) ----------
        const int msb = rb_me + slot * BB * OO;
#pragma unroll
        for (int nt = 0; nt < 2; ++nt) {
#pragma unroll
            for (int j = 0; j < 4; ++j) {
                float iT = sigm(accT[0][nt][j] + bi[nt]);
                float fT = sigm(accT[1][nt][j] + bff[nt]);
                float gT = tanh_(accT[2][nt][j] + bg[nt]);
                float oT = sigm(accT[3][nt][j] + bo[nt]);
                float c0 = fT * cT[nt][j] + iT * gT;
                float h0 = oT * tanh_(c0);

                float iL = sigm(accL[0][nt][j] + bi[nt]);
                float fL = sigm(accL[1][nt][j] + bff[nt]);
                float gL = tanh_(accL[2][nt][j] + bg[nt]);
                float oL = sigm(accL[3][nt][j] + bo[nt]);
                float c1 = fL * cL[nt][j] + iL * gL;
                float h1 = oL * tanh_(c1);

                float ct = ws0 * c0 + ws1 * c1 + bb[nt];
                float ht = ws0 * h0 + ws1 * h1 + bb[nt];
                cL[nt][j] = ct;

                if (r < 31)
                    astoref(cring + msb + (b0 + lh * 4 + j) * OO + nb + nt * 16 + lr, ct);
                out[obase[nt][j] + ww] = ht;
                lds_h[(lh * 4 + j) * 136 + nb + nt * 16 + lr] = f2bf(ht);
            }
        }
        __syncthreads();

        // rebuild h_left A-frags from LDS; publish h to ring (wave wv owns ktile wv)
#pragma unroll
        for (int kt = 0; kt < 4; ++kt) {
            const short* p = lds_h + lr * 136 + kt * 32 + lh * 8;
            hLf[kt] = *(const short8*)p;
        }
        if (r < 31) {
            union { short8 v; unsigned long long q[2]; } u;
            u.v = hLf[wv];
            unsigned long long* p =
                (unsigned long long*)(hring + msb + (b0 + lr) * OO + wv * 32 + lh * 8);
            astore64(p, u.q[0]);
            astore64(p + 1, u.q[1]);
        }
        __syncthreads();   // barrier drains vmcnt: ring stores visible before flag store

        if (tid == 0) {
            __hip_atomic_store(myprog, wsc + 1, __ATOMIC_RELAXED, __HIP_MEMORY_SCOPE_AGENT);
            if (r > 0)
                __hip_atomic_store(mycons, wsc + 1, __ATOMIC_RELAXED, __HIP_MEMORY_SCOPE_AGENT);
        }
    }
}

extern "C" void kernel_launch(void* const* d_in, const int* in_sizes, int n_in,
                              void* d_out, int out_size, void* d_ws, size_t ws_size,
                              hipStream_t stream) {
    (void)in_sizes; (void)n_in; (void)out_size; (void)ws_size;

    const float* x     = (const float*)d_in[0];
    const float* w_ii  = (const float*)d_in[1];
    const float* w_hi  = (const float*)d_in[2];
    const float* b_i   = (const float*)d_in[3];
    const float* w_if  = (const float*)d_in[4];
    const float* w_hf  = (const float*)d_in[5];
    const float* b_f   = (const float*)d_in[6];
    const float* w_ig  = (const float*)d_in[7];
    const float* w_hg  = (const float*)d_in[8];
    const float* b_g   = (const float*)d_in[9];
    const float* w_io  = (const float*)d_in[10];
    const float* w_ho  = (const float*)d_in[11];
    const float* b_o   = (const float*)d_in[12];
    const float* wsum  = (const float*)d_in[13];
    const float* bias  = (const float*)d_in[14];
    float* outp        = (float*)d_out;

    char* ws = (char*)d_ws;
    short* xTp    = (short*)ws;                       // 4 MB
    short* hringp = (short*)(ws + (4u << 20));        // 4 MB
    float* cringp = (float*)(ws + (8u << 20));        // 8 MB
    int*   flags  = (int*)(ws + (16u << 20));         // 2 KB
    int*   progp  = flags;
    int*   consp  = flags + 256;

    hipLaunchKernelGGL(mdlstm_init, dim3(8192), dim3(256), 0, stream, x, xTp, flags);

    mdlstm_main<<<dim3(256), dim3(256), 0, stream>>>(
        xTp,
        w_ii, w_hi, b_i,
        w_if, w_hf, b_f,
        w_ig, w_hg, b_g,
        w_io, w_ho, b_o,
        wsum, bias,
        hringp, cringp, progp, consp,
        outp);
}

// Round 3
// 1566.018 us; speedup vs baseline: 1.1976x; 1.1976x over previous
//
#include <hip/hip_runtime.h>

#define Hh 32
#define Ww 128
#define BB 32
#define CC 16
#define OO 128
#define DEPTH 4
#define SPIN_CAP (1 << 23)

typedef __attribute__((ext_vector_type(8))) short short8;
typedef __attribute__((ext_vector_type(4))) float f32x4;

__device__ inline short f2bf(float f) {
    unsigned u = __builtin_bit_cast(unsigned, f);
    unsigned r = (u + 0x7FFFu + ((u >> 16) & 1u)) >> 16;
    return (short)r;
}
__device__ inline float bf2f(short s) {
    unsigned u = ((unsigned)(unsigned short)s) << 16;
    return __builtin_bit_cast(float, u);
}
__device__ inline float rcp_(float x) { return __builtin_amdgcn_rcpf(x); }
__device__ inline float sigm(float x) {
    return rcp_(1.f + __builtin_amdgcn_exp2f(-1.442695041f * x));
}
__device__ inline float tanh_(float x) {
    return 1.f - 2.f * rcp_(__builtin_amdgcn_exp2f(2.885390082f * x) + 1.f);
}

__device__ inline unsigned long long aload64(const unsigned long long* p) {
    return __hip_atomic_load(p, __ATOMIC_RELAXED, __HIP_MEMORY_SCOPE_AGENT);
}
__device__ inline void astore64(unsigned long long* p, unsigned long long v) {
    __hip_atomic_store(p, v, __ATOMIC_RELAXED, __HIP_MEMORY_SCOPE_AGENT);
}

// ---- init: zero flags, transpose x (B,C,H,W) fp32 -> xT (H,W,B,C) bf16 ----
__global__ void mdlstm_init(const float* __restrict__ x, short* __restrict__ xT,
                            int* __restrict__ flags) {
    int idx = blockIdx.x * 256 + threadIdx.x;
    if (blockIdx.x == 0) {
        flags[threadIdx.x] = 0;
        flags[256 + threadIdx.x] = 0;
    }
    int w = idx & 127;
    int h = (idx >> 7) & 31;
    int c = (idx >> 12) & 15;
    int b = idx >> 16;
    float v = x[idx];
    xT[((h * Ww + w) * BB + b) * CC + c] = f2bf(v);
}

// ---- main persistent wavefront kernel: 256 blocks x 512 threads, 1 block/CU ----
__global__ void __launch_bounds__(512, 1) mdlstm_main(
    const short* __restrict__ xT,
    const float* __restrict__ w_ii, const float* __restrict__ w_hi, const float* __restrict__ b_i,
    const float* __restrict__ w_if, const float* __restrict__ w_hf, const float* __restrict__ b_f,
    const float* __restrict__ w_ig, const float* __restrict__ w_hg, const float* __restrict__ b_g,
    const float* __restrict__ w_io, const float* __restrict__ w_ho, const float* __restrict__ b_o,
    const float* __restrict__ wsum, const float* __restrict__ bias,
    short* __restrict__ hring, float* __restrict__ cring,
    int* __restrict__ prog, int* __restrict__ cons,
    float* __restrict__ out)
{
    const int chain = blockIdx.x & 7;       // d*2+s -> one XCD per chain (perf heuristic)
    const int r     = blockIdx.x >> 3;      // scan row 0..31
    const int d     = chain >> 1;
    const int s     = chain & 1;
    const int b0    = s * 16;
    const bool fy   = (d >= 2);
    const bool fx   = (d & 1);
    const int hh    = fy ? (Hh - 1 - r) : r;

    const int tid  = threadIdx.x;
    const int wv   = tid >> 6;    // 0..7: one 16-wide ntile per wave
    const int lane = tid & 63;
    const int lr   = lane & 15;   // A m / B n / D col
    const int lh   = lane >> 4;   // quad
    const int nb   = wv * 16;     // this wave's output-column base
    const int on   = nb + lr;     // this lane's output column o

    // stage[o:128][w16:16][b:16] bf16 — output staging AND h_left exchange. 64 KB.
    __shared__ short stage[OO * 16 * 16];

    // ---------- weight fragments (registers, loaded once) ----------
    const float* whp[4] = {w_hi, w_hf, w_hg, w_ho};
    const float* wip[4] = {w_ii, w_if, w_ig, w_io};
    short8 whf[4][4];   // [gate][ktile] B-frag: W[n][k]
    short8 wif_[4];     // input-proj B-frag (k<16 valid, rest 0)
#pragma unroll
    for (int g = 0; g < 4; ++g) {
#pragma unroll
        for (int kt = 0; kt < 4; ++kt) {
            const float* p = whp[g] + ((d * OO + on) * OO + kt * 32 + lh * 8);
            short8 f;
#pragma unroll
            for (int j = 0; j < 8; ++j) f[j] = f2bf(p[j]);
            whf[g][kt] = f;
        }
        short8 fi = (short8)(short)0;
        if (lh < 2) {
            const float* p = wip[g] + ((d * OO + on) * CC + lh * 8);
#pragma unroll
            for (int j = 0; j < 8; ++j) fi[j] = f2bf(p[j]);
        }
        wif_[g] = fi;
    }

    const float bi  = b_i[d * OO + on];
    const float bf_ = b_f[d * OO + on];
    const float bg_ = b_g[d * OO + on];
    const float bo_ = b_o[d * OO + on];
    const float bb_ = bias[d * OO + on];
    const float ws0 = wsum[d * 2 + 0];
    const float ws1 = wsum[d * 2 + 1];

    // flags
    int* topf      = prog + ((d * 32 + (r - 1)) * 2 + s);   // valid if r>0
    int* myprog    = prog + ((d * 32 + r) * 2 + s);
    int* mycons    = cons + ((d * 32 + r) * 2 + s);
    int* consnext  = cons + ((d * 32 + (r + 1)) * 2 + s);   // valid if r<31

    // ring bases (element units). hring: [slot][b:32][o:128] bf16.
    // cring: [slot][o:128][b:32] fp32 (vectorized over b).
    const int rb_me  = (d * 32 + r) * DEPTH * BB * OO;
    const int rb_top = (d * 32 + (r - 1)) * DEPTH * BB * OO;

    // recurrent state
    short8 hLf[4];
#pragma unroll
    for (int kt = 0; kt < 4; ++kt) hLf[kt] = (short8)(short)0;
    float cL[4] = {0.f, 0.f, 0.f, 0.f};

    int top_seen = 0, cons_seen = 0;
    const f32x4 zacc = {0.f, 0.f, 0.f, 0.f};

    for (int wsc = 0; wsc < Ww; ++wsc) {
        const int ww    = fx ? (Ww - 1 - wsc) : wsc;
        const int slot  = wsc & (DEPTH - 1);
        const int wslot = ww & 15;

        // x input fragment (A-layout, K=16 zero-padded to 32)
        short8 xf = (short8)(short)0;
        if (lh < 2) {
            const short* p = xT + ((hh * Ww + ww) * BB + b0 + lr) * CC + lh * 8;
            xf = *(const short8*)p;
        }

        // back-pressure: don't overwrite ring slot until consumer done with it
        if (r < 31 && wsc >= DEPTH) {
            const int need = wsc - DEPTH + 1;
            int spin = 0;
            while (cons_seen < need && spin < SPIN_CAP) {
                int v = 0;
                if (lane == 0) v = __hip_atomic_load(consnext, __ATOMIC_RELAXED, __HIP_MEMORY_SCOPE_AGENT);
                v = __shfl(v, 0, 64);
                if (v < need) { __builtin_amdgcn_s_sleep(1); ++spin; } else cons_seen = v;
            }
        }

        // ---------- left branch + x proj first (overlaps top-wait latency) ----------
        f32x4 ax[4], accL[4];
#pragma unroll
        for (int g = 0; g < 4; ++g)
            ax[g] = __builtin_amdgcn_mfma_f32_16x16x32_bf16(xf, wif_[g], zacc, 0, 0, 0);
#pragma unroll
        for (int g = 0; g < 4; ++g) {
            f32x4 a = ax[g];
#pragma unroll
            for (int kt = 0; kt < 4; ++kt)
                a = __builtin_amdgcn_mfma_f32_16x16x32_bf16(hLf[kt], whf[g][kt], a, 0, 0, 0);
            accL[g] = a;
        }

        // ---------- top dependency ----------
        short8 hTf[4];
        float cT[4];
        if (r > 0) {
            const int need = wsc + 1;
            int spin = 0;
            while (top_seen < need && spin < SPIN_CAP) {
                int v = 0;
                if (lane == 0) v = __hip_atomic_load(topf, __ATOMIC_RELAXED, __HIP_MEMORY_SCOPE_AGENT);
                v = __shfl(v, 0, 64);
                if (v < need) { __builtin_amdgcn_s_sleep(1); ++spin; } else top_seen = v;
            }
            const int hb = rb_top + slot * BB * OO + (b0 + lr) * OO;
#pragma unroll
            for (int kt = 0; kt < 4; ++kt) {
                const unsigned long long* p = (const unsigned long long*)(hring + hb + kt * 32 + lh * 8);
                union { unsigned long long q[2]; short8 v; } u;
                u.q[0] = aload64(p);
                u.q[1] = aload64(p + 1);
                hTf[kt] = u.v;
            }
            const unsigned long long* cp =
                (const unsigned long long*)(cring + rb_top + slot * OO * BB + on * BB + b0 + lh * 4);
            union { unsigned long long q; float f[2]; } c01, c23;
            c01.q = aload64(cp);
            c23.q = aload64(cp + 1);
            cT[0] = c01.f[0]; cT[1] = c01.f[1]; cT[2] = c23.f[0]; cT[3] = c23.f[1];
        } else {
#pragma unroll
            for (int kt = 0; kt < 4; ++kt) hTf[kt] = (short8)(short)0;
#pragma unroll
            for (int j = 0; j < 4; ++j) cT[j] = 0.f;
        }

        f32x4 accT[4];
#pragma unroll
        for (int g = 0; g < 4; ++g) {
            f32x4 a = ax[g];
#pragma unroll
            for (int kt = 0; kt < 4; ++kt)
                a = __builtin_amdgcn_mfma_f32_16x16x32_bf16(hTf[kt], whf[g][kt], a, 0, 0, 0);
            accT[g] = a;
        }

        // ---------- elementwise LSTM cell (D-layout: col=on, row b = lh*4+j) ----------
        float ctv[4];
        union { short sh[4]; unsigned long long q; } hpack;
#pragma unroll
        for (int j = 0; j < 4; ++j) {
            float iT = sigm(accT[0][j] + bi);
            float fT = sigm(accT[1][j] + bf_);
            float gT = tanh_(accT[2][j] + bg_);
            float oT = sigm(accT[3][j] + bo_);
            float c0 = fT * cT[j] + iT * gT;
            float h0 = oT * tanh_(c0);

            float iL = sigm(accL[0][j] + bi);
            float fL = sigm(accL[1][j] + bf_);
            float gL = tanh_(accL[2][j] + bg_);
            float oL = sigm(accL[3][j] + bo_);
            float c1 = fL * cL[j] + iL * gL;
            float h1 = oL * tanh_(c1);

            float ct = ws0 * c0 + ws1 * c1 + bb_;
            float ht = ws0 * h0 + ws1 * h1 + bb_;
            cL[j] = ct;
            ctv[j] = ct;
            hpack.sh[j] = f2bf(ht);
        }

        // stage write: one 8B LDS write (4 consecutive b)
        *(unsigned long long*)&stage[(on * 16 + wslot) * 16 + lh * 4] = hpack.q;

        if (r < 31) {
            union { float f[2]; unsigned long long q; } p01, p23;
            p01.f[0] = ctv[0]; p01.f[1] = ctv[1];
            p23.f[0] = ctv[2]; p23.f[1] = ctv[3];
            unsigned long long* cp =
                (unsigned long long*)(cring + rb_me + slot * OO * BB + on * BB + b0 + lh * 4);
            astore64(cp, p01.q);
            astore64(cp + 1, p23.q);
        }

        __syncthreads();

        // rebuild h_left A-frags from stage
#pragma unroll
        for (int kt = 0; kt < 4; ++kt) {
            short8 f;
#pragma unroll
            for (int jj = 0; jj < 8; ++jj)
                f[jj] = stage[((kt * 32 + lh * 8 + jj) * 16 + wslot) * 16 + lr];
            hLf[kt] = f;
        }

        // publish h to ring (waves 0..3 own ktile wv)
        if (r < 31 && wv < 4) {
            union { short8 v; unsigned long long q[2]; } u;
            u.v = hLf[wv];
            unsigned long long* hp =
                (unsigned long long*)(hring + rb_me + slot * BB * OO + (b0 + lr) * OO + wv * 32 + lh * 8);
            astore64(hp, u.q[0]);
            astore64(hp + 1, u.q[1]);
        }

        // output dump every 16 steps: fully-written 64B lines, coalesced quads
        if ((wsc & 15) == 15) {
            const int wbase = ww & ~15;
            const int q  = tid & 3;
            const int r0 = tid >> 2;     // 0..127
#pragma unroll
            for (int i = 0; i < 16; ++i) {
                const int row = r0 + (i << 7);   // 0..2047
                const int o = row >> 4;
                const int b = row & 15;
                f32x4 v;
#pragma unroll
                for (int k = 0; k < 4; ++k)
                    v[k] = bf2f(stage[(o * 16 + q * 4 + k) * 16 + b]);
                float* op = out + ((size_t)((d * OO + o) * BB + b0 + b)) * (Hh * Ww)
                                + hh * Ww + wbase + q * 4;
                *(f32x4*)op = v;
            }
        }

        __syncthreads();   // drains ring stores before flag store; protects stage WAR

        if (tid == 0) {
            __hip_atomic_store(myprog, wsc + 1, __ATOMIC_RELAXED, __HIP_MEMORY_SCOPE_AGENT);
            if (r > 0)
                __hip_atomic_store(mycons, wsc + 1, __ATOMIC_RELAXED, __HIP_MEMORY_SCOPE_AGENT);
        }
    }
}

extern "C" void kernel_launch(void* const* d_in, const int* in_sizes, int n_in,
                              void* d_out, int out_size, void* d_ws, size_t ws_size,
                              hipStream_t stream) {
    (void)in_sizes; (void)n_in; (void)out_size; (void)ws_size;

    const float* x     = (const float*)d_in[0];
    const float* w_ii  = (const float*)d_in[1];
    const float* w_hi  = (const float*)d_in[2];
    const float* b_i   = (const float*)d_in[3];
    const float* w_if  = (const float*)d_in[4];
    const float* w_hf  = (const float*)d_in[5];
    const float* b_f   = (const float*)d_in[6];
    const float* w_ig  = (const float*)d_in[7];
    const float* w_hg  = (const float*)d_in[8];
    const float* b_g   = (const float*)d_in[9];
    const float* w_io  = (const float*)d_in[10];
    const float* w_ho  = (const float*)d_in[11];
    const float* b_o   = (const float*)d_in[12];
    const float* wsum  = (const float*)d_in[13];
    const float* bias  = (const float*)d_in[14];
    float* outp        = (float*)d_out;

    char* ws = (char*)d_ws;
    short* xTp    = (short*)ws;                       // 4 MB
    short* hringp = (short*)(ws + (4u << 20));        // 4 MB
    float* cringp = (float*)(ws + (8u << 20));        // 8 MB
    int*   flags  = (int*)(ws + (16u << 20));         // 2 KB
    int*   progp  = flags;
    int*   consp  = flags + 256;

    hipLaunchKernelGGL(mdlstm_init, dim3(8192), dim3(256), 0, stream, x, xTp, flags);

    mdlstm_main<<<dim3(256), dim3(512), 0, stream>>>(
        xTp,
        w_ii, w_hi, b_i,
        w_if, w_hf, b_f,
        w_ig, w_hg, b_g,
        w_io, w_ho, b_o,
        wsum, bias,
        hringp, cringp, progp, consp,
        outp);
}